// Round 6
// baseline (1259.553 us; speedup 1.0000x reference)
//
#include <hip/hip_runtime.h>
#include <math.h>

#define B_ 8
#define N_ 16384
#define D_ 384
#define TD_ 1152
#define S_ 64                         /* kA slices per batch */
#define CTXP_ELEMS (B_*8*S_*48*48)    /* 9437184 fp32: [bh][s][d][c] partials */
#define ZP_ELEMS   (B_*8*S_*48)       /* 196608 fp32:  [bh][s][c] partials   */

typedef __attribute__((ext_vector_type(8))) short short8;
typedef __attribute__((ext_vector_type(4))) float f32x4;
typedef __attribute__((ext_vector_type(4))) unsigned short us4;
typedef __attribute__((ext_vector_type(8))) unsigned short us8;

__device__ __forceinline__ unsigned short f2bf(float f){
    union { float f; unsigned u; } v; v.f = f;
    unsigned r = v.u + 0x7FFFu + ((v.u >> 16) & 1u);   // RNE
    return (unsigned short)(r >> 16);
}
__device__ __forceinline__ float bf2f(unsigned short h){
    union { unsigned u; float f; } v; v.u = ((unsigned)h) << 16;
    return v.f;
}

#define MFMA(a,b,c) __builtin_amdgcn_mfma_f32_16x16x32_bf16((a),(b),(c),0,0,0)

// ---------------------------------------------------------------------------
// kP: transpose + bf16-ify weights. WqkvT[col][d] (1152x384), WpT[col][d] (384x384)
// ---------------------------------------------------------------------------
__global__ void kP(const float* __restrict__ Wqkv, const float* __restrict__ Wp,
                   unsigned short* __restrict__ WqkvT, unsigned short* __restrict__ WpT)
{
    __shared__ float t[32][33];
    int bi = blockIdx.x;
    const float* src; unsigned short* dst; int ldS, c0, d0;
    if (bi < 432) { src = Wqkv; dst = WqkvT; ldS = 1152; c0 = (bi % 36) * 32; d0 = (bi / 36) * 32; }
    else { bi -= 432; src = Wp; dst = WpT; ldS = 384; c0 = (bi % 12) * 32; d0 = (bi / 12) * 32; }
    const int cx = threadIdx.x & 31, ry = threadIdx.x >> 5;
#pragma unroll
    for (int k = 0; k < 4; ++k) {
        int r = ry + k * 8;
        t[r][cx] = src[(size_t)(d0 + r) * ldS + c0 + cx];
    }
    __syncthreads();
#pragma unroll
    for (int k = 0; k < 4; ++k) {
        int r = ry + k * 8;
        dst[(size_t)(c0 + r) * 384 + d0 + cx] = f2bf(t[cx][r]);
    }
}

// ---------------------------------------------------------------------------
// kA: per block (512 thr = 8 waves, wave = head): 8 token-tiles of 32.
// LDS 72.5 KB -> 2 blocks/CU, 4 waves/SIMD (was 1 block, 2 waves/SIMD).
// T14 pipeline: stage-write(g) | barrier | issue-loads(g+1) | kv GEMM |
// exp->kv(swizzled) | barrier | ctx MFMA.  Partials per slice, nt stores.
// grid = 512 (64 slices per batch x 8 tiles of 32 tokens).
// ---------------------------------------------------------------------------
__global__ __launch_bounds__(512, 4) void kA(const float* __restrict__ x,
        const unsigned short* __restrict__ WqkvT,
        float* __restrict__ ctxP, float* __restrict__ ZP)
{
    __shared__ __align__(16) unsigned short xs[32 * 392];    // x tile, [t][d], bf16 (24.5 KB)
    __shared__ __align__(16) unsigned short kv[8 * 96 * 32]; // per-wave [row96][t32], XOR-swizzled (48 KB)

    const int tid = threadIdx.x;
    const int w   = tid >> 6;       // wave = head
    const int l   = tid & 63;
    const int q   = l >> 4;
    const int c16 = l & 15;
    const int blk = blockIdx.x;
    const int b   = blk >> 6;
    const int s   = blk & 63;       // token-slice id (partial index)
    unsigned short* kvw = kv + w * (96 * 32);

    f32x4 ctxacc[3][3];
    float zp[3] = {0.f, 0.f, 0.f};
#pragma unroll
    for (int i = 0; i < 3; ++i)
#pragma unroll
        for (int j = 0; j < 3; ++j) ctxacc[i][j] = (f32x4){0.f, 0.f, 0.f, 0.f};

    const int st = tid >> 4, sq = tid & 15;   // 32 rows x 16 threads/row

    // --- T14 stage registers: tile g's 32 x-rows held as fp32 across the loop ---
    f32x4 r[6];
    {   // prologue: issue loads for tile 0
        const float* xg = x + ((size_t)b * 16384 + (size_t)s * 256 + st) * 384 + sq * 4;
#pragma unroll
        for (int i = 0; i < 6; ++i)
            r[i] = __builtin_nontemporal_load((const f32x4*)(xg + i * 64));
    }

    for (int g = 0; g < 8; ++g) {
        // [A] convert + write tile g into xs
        {
            unsigned short* xw = xs + st * 392 + sq * 4;
#pragma unroll
            for (int i = 0; i < 6; ++i) {
                f32x4 v = r[i];
                us4 o; o.x = f2bf(v.x); o.y = f2bf(v.y); o.z = f2bf(v.z); o.w = f2bf(v.w);
                *(us4*)(xw + i * 64) = o;
            }
        }
        __syncthreads();   // [B] xs ready

        // [C] issue next tile's global loads; fly under [D]+[E]
        if (g + 1 < 8) {
            const float* xg = x + ((size_t)b * 16384 + (size_t)s * 256 + (g + 1) * 32 + st) * 384 + sq * 4;
#pragma unroll
            for (int i = 0; i < 6; ++i)
                r[i] = __builtin_nontemporal_load((const f32x4*)(xg + i * 64));
        }

        // [D] k,v GEMM: 32 tok x 96 cols (this head's k:48 + v:48), K=384
        f32x4 kva[2][6];
#pragma unroll
        for (int mt = 0; mt < 2; ++mt)
#pragma unroll
            for (int j = 0; j < 6; ++j) kva[mt][j] = (f32x4){0.f, 0.f, 0.f, 0.f};

#pragma unroll
        for (int ks = 0; ks < 12; ++ks) {
            short8 a[2];
#pragma unroll
            for (int mt = 0; mt < 2; ++mt)
                a[mt] = *(const short8*)(xs + (mt * 16 + c16) * 392 + ks * 32 + q * 8);
#pragma unroll
            for (int j = 0; j < 6; ++j) {
                const int colrow = (j < 3) ? (384 + w * 48 + j * 16 + c16)
                                           : (768 + w * 48 + (j - 3) * 16 + c16);
                short8 bf = *(const short8*)(WqkvT + (size_t)colrow * 384 + ks * 32 + q * 8);
#pragma unroll
                for (int mt = 0; mt < 2; ++mt)
                    kva[mt][j] = MFMA(a[mt], bf, kva[mt][j]);
            }
        }

        // [E] exp(k), pack bf16, write swizzled [row][t32] (4 chunks of 8 tokens)
#pragma unroll
        for (int mt = 0; mt < 2; ++mt) {
            const int chunk = 2 * mt + (q >> 1);
            const int tin = (q & 1) * 4;
#pragma unroll
            for (int j = 0; j < 6; ++j) {
                f32x4 vv = kva[mt][j];
                us4 o;
                int row;
                if (j < 3) {
                    row = j * 16 + c16;
                    float e0 = __expf(vv.x), e1 = __expf(vv.y), e2 = __expf(vv.z), e3 = __expf(vv.w);
                    zp[j] += (e0 + e1) + (e2 + e3);
                    o.x = f2bf(e0); o.y = f2bf(e1); o.z = f2bf(e2); o.w = f2bf(e3);
                } else {
                    row = 48 + (j - 3) * 16 + c16;
                    o.x = f2bf(vv.x); o.y = f2bf(vv.y); o.z = f2bf(vv.z); o.w = f2bf(vv.w);
                }
                *(us4*)(kvw + row * 32 + ((chunk ^ (row & 3)) << 3) + tin) = o;
            }
        }
        __syncthreads();   // [F] protects xs; kv is wave-private

        // [G] ctx MFMA: ctx[c][d] += ek^T . v over this tile's 32 tokens (K=32)
        {
            short8 af[3], bf2[3];
#pragma unroll
            for (int i = 0; i < 3; ++i) {
                const int ra = i * 16 + c16;
                af[i]  = *(const short8*)(kvw + ra * 32 + ((q ^ (ra & 3)) << 3));
                const int rb = 48 + i * 16 + c16;
                bf2[i] = *(const short8*)(kvw + rb * 32 + ((q ^ (rb & 3)) << 3));
            }
#pragma unroll
            for (int ct = 0; ct < 3; ++ct)
#pragma unroll
                for (int dt = 0; dt < 3; ++dt)
                    ctxacc[ct][dt] = MFMA(af[ct], bf2[dt], ctxacc[ct][dt]);
        }
    }

    // --- finalize: plain nt stores of partials (no atomics) ---
#pragma unroll
    for (int j = 0; j < 3; ++j) {
        float v = zp[j];
        v += __shfl_xor(v, 16);
        v += __shfl_xor(v, 32);
        if (l < 16)
            __builtin_nontemporal_store(v,
                &ZP[((size_t)(b * 8 + w) * S_ + s) * 48 + j * 16 + c16]);
    }
#pragma unroll
    for (int ct = 0; ct < 3; ++ct)
#pragma unroll
        for (int dt = 0; dt < 3; ++dt) {
            const int d  = dt * 16 + c16;
            const int c0 = ct * 16 + q * 4;
            float* dst = ctxP + (((size_t)(b * 8 + w) * S_ + s) * 2304 + d * 48 + c0);
            __builtin_nontemporal_store(ctxacc[ct][dt], (f32x4*)dst);
        }
}

// ---------------------------------------------------------------------------
// kG: per block = one (b,h): reduce partials -> ctx̂ (LDS), then fold Wp:
//   GT[b][o][h*48+c] = bf16( sum_d (ctx_sum[d][c] * zinv[c]) * WpT[o][h*48+d] )
// kC's proj then needs only GT (K=384), eliminating the y-GEMM entirely.
// grid = 64, block = 384 (one thread per output column o).
// ---------------------------------------------------------------------------
__global__ __launch_bounds__(384) void kG(const float* __restrict__ ctxP,
        const float* __restrict__ ZP, const unsigned short* __restrict__ WpT,
        unsigned short* __restrict__ GT)
{
    __shared__ float ctxL[2304];   // [d][c] summed partials
    __shared__ float zinv[48];
    const int bh = blockIdx.x, b = bh >> 3, h = bh & 7;
    const int t = threadIdx.x;

    if (t < 48) {
        float z = 0.f;
        for (int s = 0; s < S_; ++s)
            z += ZP[((size_t)bh * S_ + s) * 48 + t];
        zinv[t] = 1.0f / z;
    }
#pragma unroll
    for (int i = 0; i < 6; ++i) {
        const int f = i * 384 + t;
        float sum = 0.f;
        for (int s = 0; s < S_; ++s)
            sum += __builtin_nontemporal_load(ctxP + (size_t)(bh * S_ + s) * 2304 + f);
        ctxL[f] = sum;
    }
    __syncthreads();

    float wpf[48];
    const unsigned short* wp = WpT + (size_t)t * 384 + h * 48;
#pragma unroll
    for (int d = 0; d < 48; ++d) wpf[d] = bf2f(wp[d]);

    unsigned short* gout = GT + ((size_t)b * 384 + t) * 384 + h * 48;
#pragma unroll
    for (int c8 = 0; c8 < 6; ++c8) {
        us8 o;
#pragma unroll
        for (int e = 0; e < 8; ++e) {
            const int c = c8 * 8 + e;
            float acc = 0.f;
#pragma unroll
            for (int d = 0; d < 48; ++d)
                acc += ctxL[d * 48 + c] * wpf[d];
            o[e] = f2bf(acc * zinv[c]);
        }
        *(us8*)(gout + c8 * 8) = o;
    }
}

// ---------------------------------------------------------------------------
// kC: per 32-token block (256 thr = 4 waves, wave = 2 heads):
// q-GEMM (MFMA) -> in-register softmax (shfl) -> q̂ into xs -> proj vs GT (+bias).
// y-GEMM fused away via GT; qs buffer deleted; LDS 24.5 KB -> ~5 blocks/CU.
// grid = 4096.
// ---------------------------------------------------------------------------
__global__ __launch_bounds__(256, 4) void kC(const float* __restrict__ x,
        const unsigned short* __restrict__ WqkvT,
        const unsigned short* __restrict__ GT,
        const float* __restrict__ bp, float* __restrict__ out)
{
    __shared__ __align__(16) unsigned short xs[32 * 392];   // x tile; reused as q̂ tile

    const int tid = threadIdx.x;
    const int w   = tid >> 6;
    const int l   = tid & 63;
    const int q   = l >> 4;
    const int c16 = l & 15;
    const int blk = blockIdx.x;
    const size_t tok0 = (size_t)blk * 32;
    const int b = blk >> 9;

    {   // stage x (non-temporal: block-exclusive rows)
        const int st = tid >> 3, sq = tid & 7;
        const float* xg = x + (tok0 + st) * 384 + sq * 4;
        unsigned short* xw = xs + st * 392 + sq * 4;
#pragma unroll
        for (int i = 0; i < 12; ++i) {
            f32x4 v = __builtin_nontemporal_load((const f32x4*)(xg + i * 32));
            us4 o; o.x = f2bf(v.x); o.y = f2bf(v.y); o.z = f2bf(v.z); o.w = f2bf(v.w);
            *(us4*)(xw + i * 32) = o;
        }
    }
    __syncthreads();

    // --- q-GEMM: 32 tok x 96 cols per wave (heads 2w, 2w+1), K=384 ---
    f32x4 acc[2][6];
#pragma unroll
    for (int mt = 0; mt < 2; ++mt)
#pragma unroll
        for (int j = 0; j < 6; ++j) acc[mt][j] = (f32x4){0.f, 0.f, 0.f, 0.f};

#pragma unroll
    for (int ks = 0; ks < 12; ++ks) {
        short8 a0 = *(const short8*)(xs + (c16) * 392 + ks * 32 + q * 8);
        short8 a1 = *(const short8*)(xs + (16 + c16) * 392 + ks * 32 + q * 8);
#pragma unroll
        for (int j = 0; j < 6; ++j) {
            const int nt = w * 6 + j;
            short8 bf = *(const short8*)(WqkvT + (size_t)(nt * 16 + c16) * 384 + ks * 32 + q * 8);
            acc[0][j] = MFMA(a0, bf, acc[0][j]);
            acc[1][j] = MFMA(a1, bf, acc[1][j]);
        }
    }
    __syncthreads();    // xs (x data) dead -> reuse for q̂

    // --- softmax over C=48 per (token, head); write q̂ into xs[t][h*48+c] ---
#pragma unroll
    for (int hh = 0; hh < 2; ++hh) {
        const int h = 2 * w + hh;
        f32x4 e[2][3];
#pragma unroll
        for (int mt = 0; mt < 2; ++mt)
#pragma unroll
            for (int jj = 0; jj < 3; ++jj) {
                f32x4 vv = acc[mt][hh * 3 + jj];
                e[mt][jj].x = __expf(vv.x); e[mt][jj].y = __expf(vv.y);
                e[mt][jj].z = __expf(vv.z); e[mt][jj].w = __expf(vv.w);
            }
#pragma unroll
        for (int mt = 0; mt < 2; ++mt)
#pragma unroll
            for (int r = 0; r < 4; ++r) {
                float ss = e[mt][0][r] + e[mt][1][r] + e[mt][2][r];
                ss += __shfl_xor(ss, 1); ss += __shfl_xor(ss, 2);
                ss += __shfl_xor(ss, 4); ss += __shfl_xor(ss, 8);
                const float inv = 1.0f / ss;
                e[mt][0][r] *= inv; e[mt][1][r] *= inv; e[mt][2][r] *= inv;
            }
#pragma unroll
        for (int mt = 0; mt < 2; ++mt)
#pragma unroll
            for (int jj = 0; jj < 3; ++jj) {
                const int c = jj * 16 + c16;
#pragma unroll
                for (int r = 0; r < 4; ++r) {
                    const int t = mt * 16 + q * 4 + r;
                    xs[t * 392 + h * 48 + c] = f2bf(e[mt][jj][r]);
                }
            }
    }
    __syncthreads();

    // --- proj: out = q̂ @ GT[b] + bias, K=384, 32 tok x 96 cols per wave ---
    f32x4 po[2][6];
#pragma unroll
    for (int mt = 0; mt < 2; ++mt)
#pragma unroll
        for (int j = 0; j < 6; ++j) po[mt][j] = (f32x4){0.f, 0.f, 0.f, 0.f};

#pragma unroll
    for (int ks = 0; ks < 12; ++ks) {
        short8 a0 = *(const short8*)(xs + (c16) * 392 + ks * 32 + q * 8);
        short8 a1 = *(const short8*)(xs + (16 + c16) * 392 + ks * 32 + q * 8);
#pragma unroll
        for (int j = 0; j < 6; ++j) {
            const int nt = w * 6 + j;
            short8 bf = *(const short8*)(GT + ((size_t)(b * 384 + nt * 16 + c16)) * 384 + ks * 32 + q * 8);
            po[0][j] = MFMA(a0, bf, po[0][j]);
            po[1][j] = MFMA(a1, bf, po[1][j]);
        }
    }

    // --- epilogue: bias + non-temporal store ---
#pragma unroll
    for (int j = 0; j < 6; ++j) {
        const int col = (w * 6 + j) * 16 + c16;
        const float bv = bp[col];
#pragma unroll
        for (int mt = 0; mt < 2; ++mt)
#pragma unroll
            for (int r = 0; r < 4; ++r) {
                const int t = mt * 16 + q * 4 + r;
                __builtin_nontemporal_store(po[mt][j][r] + bv,
                                            &out[(tok0 + t) * 384 + col]);
            }
    }
}

// ---------------------------------------------------------------------------
extern "C" void kernel_launch(void* const* d_in, const int* in_sizes, int n_in,
                              void* d_out, int out_size, void* d_ws, size_t ws_size,
                              hipStream_t stream)
{
    (void)in_sizes; (void)n_in; (void)out_size; (void)ws_size;
    const float* x    = (const float*)d_in[0];
    const float* Wqkv = (const float*)d_in[1];
    const float* Wp   = (const float*)d_in[2];
    const float* bp   = (const float*)d_in[3];
    float* out = (float*)d_out;

    char* p = (char*)d_ws;
    float* ctxP = (float*)p;                     p += (size_t)CTXP_ELEMS * 4;  // 37.75 MB
    float* ZP   = (float*)p;                     p += (size_t)ZP_ELEMS * 4;    // 786 KB
    unsigned short* WqkvT = (unsigned short*)p;  p += (size_t)TD_ * D_ * 2;    // 884736 B
    unsigned short* WpT   = (unsigned short*)p;  p += (size_t)D_ * D_ * 2;     // 294912 B
    unsigned short* GT    = (unsigned short*)p;                                // 2.36 MB

    kP<<<dim3(576), dim3(256), 0, stream>>>(Wqkv, Wp, WqkvT, WpT);
    kA<<<dim3(512), dim3(512), 0, stream>>>(x, WqkvT, ctxP, ZP);
    kG<<<dim3(64), dim3(384), 0, stream>>>(ctxP, ZP, WpT, GT);
    kC<<<dim3(4096), dim3(256), 0, stream>>>(x, WqkvT, GT, bp, out);
}

// Round 9
// 857.013 us; speedup vs baseline: 1.4697x; 1.4697x over previous
//
#include <hip/hip_runtime.h>
#include <math.h>

#define B_ 8
#define N_ 16384
#define D_ 384
#define TD_ 1152
#define S_ 32                         /* kA slices per batch */
#define CTXP_ELEMS (B_*8*S_*48*48)    /* 4718592 fp32: [bh][s][d][c] partials */
#define ZP_ELEMS   (B_*8*S_*48)       /* 98304 fp32:   [bh][s][c] partials   */

typedef __attribute__((ext_vector_type(8))) short short8;
typedef __attribute__((ext_vector_type(4))) float f32x4;
typedef __attribute__((ext_vector_type(4))) unsigned short us4;
typedef __attribute__((ext_vector_type(8))) unsigned short us8;

__device__ __forceinline__ unsigned short f2bf(float f){
    union { float f; unsigned u; } v; v.f = f;
    unsigned r = v.u + 0x7FFFu + ((v.u >> 16) & 1u);   // RNE
    return (unsigned short)(r >> 16);
}
__device__ __forceinline__ float bf2f(unsigned short h){
    union { unsigned u; float f; } v; v.u = ((unsigned)h) << 16;
    return v.f;
}

#define MFMA(a,b,c) __builtin_amdgcn_mfma_f32_16x16x32_bf16((a),(b),(c),0,0,0)

// ---------------------------------------------------------------------------
// kP: transpose + bf16-ify weights. WqkvT[col][d] (1152x384), WpT[col][d] (384x384)
// ---------------------------------------------------------------------------
__global__ void kP(const float* __restrict__ Wqkv, const float* __restrict__ Wp,
                   unsigned short* __restrict__ WqkvT, unsigned short* __restrict__ WpT)
{
    __shared__ float t[32][33];
    int bi = blockIdx.x;
    const float* src; unsigned short* dst; int ldS, c0, d0;
    if (bi < 432) { src = Wqkv; dst = WqkvT; ldS = 1152; c0 = (bi % 36) * 32; d0 = (bi / 36) * 32; }
    else { bi -= 432; src = Wp; dst = WpT; ldS = 384; c0 = (bi % 12) * 32; d0 = (bi / 12) * 32; }
    const int cx = threadIdx.x & 31, ry = threadIdx.x >> 5;
#pragma unroll
    for (int k = 0; k < 4; ++k) {
        int r = ry + k * 8;
        t[r][cx] = src[(size_t)(d0 + r) * ldS + c0 + cx];
    }
    __syncthreads();
#pragma unroll
    for (int k = 0; k < 4; ++k) {
        int r = ry + k * 8;
        dst[(size_t)(c0 + r) * 384 + d0 + cx] = f2bf(t[cx][r]);
    }
}

// ---------------------------------------------------------------------------
// kA: per block (512 thr = 8 waves, wave = head): 8 token-tiles of 64.
// MEASURED-GOOD R3 config: __launch_bounds__(512,2) -> VGPR 128, no spill.
// (R4's (512,4) capped VGPR at 64 -> scratch spill -> FETCH 1.37GB. Reverted.)
// T14 pipeline: stage-write(g) | barrier | issue-loads(g+1) | kv GEMM |
// exp->kv(swizzled) | barrier | ctx MFMA.  Partials per slice, nt stores.
// grid = 256 (32 slices per batch x 8 tiles of 64 tokens).
// ---------------------------------------------------------------------------
__global__ __launch_bounds__(512, 2) void kA(const float* __restrict__ x,
        const unsigned short* __restrict__ WqkvT,
        float* __restrict__ ctxP, float* __restrict__ ZP)
{
    __shared__ __align__(16) unsigned short xs[64 * 392];    // x tile, [t][d], bf16
    __shared__ __align__(16) unsigned short kv[8 * 96 * 64]; // per-wave [row96][t64], XOR-swizzled

    const int tid = threadIdx.x;
    const int w   = tid >> 6;       // wave = head
    const int l   = tid & 63;
    const int q   = l >> 4;
    const int c16 = l & 15;
    const int blk = blockIdx.x;
    const int b   = blk >> 5;
    const int s   = blk & 31;       // token-slice id (partial index)
    const int tbase = s * 8;
    unsigned short* kvw = kv + w * (96 * 64);

    f32x4 ctxacc[3][3];
    float zp[3] = {0.f, 0.f, 0.f};
#pragma unroll
    for (int i = 0; i < 3; ++i)
#pragma unroll
        for (int j = 0; j < 3; ++j) ctxacc[i][j] = (f32x4){0.f, 0.f, 0.f, 0.f};

    const int st = tid >> 3, sq = tid & 7;

    // --- T14 stage registers: tile g's x rows held as fp32 across the loop ---
    f32x4 r[12];
    {   // prologue: issue loads for tile 0 (latency exposed once per block)
        const float* xg = x + ((size_t)b * 16384 + (size_t)tbase * 64 + st) * 384 + sq * 4;
#pragma unroll
        for (int i = 0; i < 12; ++i)
            r[i] = __builtin_nontemporal_load((const f32x4*)(xg + i * 32));
    }

    for (int g = 0; g < 8; ++g) {
        // [A] convert + write tile g into xs (all waves passed [F](g-1): xs free)
        {
            unsigned short* xw = xs + st * 392 + sq * 4;
#pragma unroll
            for (int i = 0; i < 12; ++i) {
                f32x4 v = r[i];
                us4 o; o.x = f2bf(v.x); o.y = f2bf(v.y); o.z = f2bf(v.z); o.w = f2bf(v.w);
                *(us4*)(xw + i * 32) = o;
            }
        }
        __syncthreads();   // [B] xs ready for all waves

        // [C] issue next tile's global loads; they stay in flight under [D]+[E]
        if (g + 1 < 8) {
            const float* xg = x + ((size_t)b * 16384 + (size_t)(tbase + g + 1) * 64 + st) * 384 + sq * 4;
#pragma unroll
            for (int i = 0; i < 12; ++i)
                r[i] = __builtin_nontemporal_load((const f32x4*)(xg + i * 32));
        }

        // [D] k,v GEMM: 64 tok x 96 cols (this head's k:48 + v:48), K=384
        f32x4 kva[4][6];
#pragma unroll
        for (int mt = 0; mt < 4; ++mt)
#pragma unroll
            for (int j = 0; j < 6; ++j) kva[mt][j] = (f32x4){0.f, 0.f, 0.f, 0.f};

#pragma unroll
        for (int ks = 0; ks < 12; ++ks) {
            short8 a[4];
#pragma unroll
            for (int mt = 0; mt < 4; ++mt)
                a[mt] = *(const short8*)(xs + (mt * 16 + c16) * 392 + ks * 32 + q * 8);
#pragma unroll
            for (int j = 0; j < 6; ++j) {
                const int colrow = (j < 3) ? (384 + w * 48 + j * 16 + c16)
                                           : (768 + w * 48 + (j - 3) * 16 + c16);
                short8 bf = *(const short8*)(WqkvT + (size_t)colrow * 384 + ks * 32 + q * 8);
#pragma unroll
                for (int mt = 0; mt < 4; ++mt)
                    kva[mt][j] = MFMA(a[mt], bf, kva[mt][j]);
            }
        }

        // [E] exp(k), pack bf16, write swizzled [row][t]
#pragma unroll
        for (int mt = 0; mt < 4; ++mt) {
            const int chunk = 2 * mt + (q >> 1);
            const int tin = (q & 1) * 4;
#pragma unroll
            for (int j = 0; j < 6; ++j) {
                f32x4 vv = kva[mt][j];
                us4 o;
                int row;
                if (j < 3) {
                    row = j * 16 + c16;
                    float e0 = __expf(vv.x), e1 = __expf(vv.y), e2 = __expf(vv.z), e3 = __expf(vv.w);
                    zp[j] += (e0 + e1) + (e2 + e3);
                    o.x = f2bf(e0); o.y = f2bf(e1); o.z = f2bf(e2); o.w = f2bf(e3);
                } else {
                    row = 48 + (j - 3) * 16 + c16;
                    o.x = f2bf(vv.x); o.y = f2bf(vv.y); o.z = f2bf(vv.z); o.w = f2bf(vv.w);
                }
                *(us4*)(kvw + row * 64 + ((chunk ^ (row & 7)) << 3) + tin) = o;
            }
        }
        __syncthreads();   // [F] protects xs ([A] of g+1); kv is wave-private

        // [G] ctx MFMA: ctx[c][d] += ek^T . v over this tile's 64 tokens
#pragma unroll
        for (int kt = 0; kt < 2; ++kt) {
            short8 af[3], bf2[3];
#pragma unroll
            for (int i = 0; i < 3; ++i) {
                const int ra = i * 16 + c16;
                af[i]  = *(const short8*)(kvw + ra * 64 + (((kt * 4 + q) ^ (ra & 7)) << 3));
                const int rb = 48 + i * 16 + c16;
                bf2[i] = *(const short8*)(kvw + rb * 64 + (((kt * 4 + q) ^ (rb & 7)) << 3));
            }
#pragma unroll
            for (int ct = 0; ct < 3; ++ct)
#pragma unroll
                for (int dt = 0; dt < 3; ++dt)
                    ctxacc[ct][dt] = MFMA(af[ct], bf2[dt], ctxacc[ct][dt]);
        }
    }

    // --- finalize: plain nt stores of partials (no atomics, no contention) ---
#pragma unroll
    for (int j = 0; j < 3; ++j) {
        float v = zp[j];
        v += __shfl_xor(v, 16);
        v += __shfl_xor(v, 32);
        if (l < 16)
            __builtin_nontemporal_store(v,
                &ZP[((size_t)(b * 8 + w) * S_ + s) * 48 + j * 16 + c16]);
    }
#pragma unroll
    for (int ct = 0; ct < 3; ++ct)
#pragma unroll
        for (int dt = 0; dt < 3; ++dt) {
            const int d  = dt * 16 + c16;
            const int c0 = ct * 16 + q * 4;
            float* dst = ctxP + (((size_t)(b * 8 + w) * S_ + s) * 2304 + d * 48 + c0);
            __builtin_nontemporal_store(ctxacc[ct][dt], (f32x4*)dst);
        }
}

// ---------------------------------------------------------------------------
// kG: per block = one (b,h): reduce partials -> ctx̂ (LDS), then fold Wp:
//   GT[b][o][h*48+c] = bf16( sum_d (ctx_sum[d][c] * zinv[c]) * WpT[o][h*48+d] )
// kC's proj then needs only GT (K=384), eliminating the y-GEMM entirely.
// grid = 64, block = 384 (one thread per output column o).
// ---------------------------------------------------------------------------
__global__ __launch_bounds__(384) void kG(const float* __restrict__ ctxP,
        const float* __restrict__ ZP, const unsigned short* __restrict__ WpT,
        unsigned short* __restrict__ GT)
{
    __shared__ float ctxL[2304];   // [d][c] summed partials
    __shared__ float zinv[48];
    const int bh = blockIdx.x, b = bh >> 3, h = bh & 7;
    const int t = threadIdx.x;

    if (t < 48) {
        float z = 0.f;
        for (int s = 0; s < S_; ++s)
            z += ZP[((size_t)bh * S_ + s) * 48 + t];
        zinv[t] = 1.0f / z;
    }
#pragma unroll
    for (int i = 0; i < 6; ++i) {
        const int f = i * 384 + t;
        float sum = 0.f;
        for (int s = 0; s < S_; ++s)
            sum += __builtin_nontemporal_load(ctxP + (size_t)(bh * S_ + s) * 2304 + f);
        ctxL[f] = sum;
    }
    __syncthreads();

    float wpf[48];
    const unsigned short* wp = WpT + (size_t)t * 384 + h * 48;
#pragma unroll
    for (int d = 0; d < 48; ++d) wpf[d] = bf2f(wp[d]);

    unsigned short* gout = GT + ((size_t)b * 384 + t) * 384 + h * 48;
#pragma unroll
    for (int c8 = 0; c8 < 6; ++c8) {
        us8 o;
#pragma unroll
        for (int e = 0; e < 8; ++e) {
            const int c = c8 * 8 + e;
            float acc = 0.f;
#pragma unroll
            for (int d = 0; d < 48; ++d)
                acc += ctxL[d * 48 + c] * wpf[d];
            o[e] = f2bf(acc * zinv[c]);
        }
        *(us8*)(gout + c8 * 8) = o;
    }
}

// ---------------------------------------------------------------------------
// kC: per 32-token block (256 thr = 4 waves, wave = 2 heads):
// q-GEMM (MFMA) -> in-register softmax (shfl) -> q̂ into xs -> proj vs GT (+bias).
// y-GEMM fused away via GT; qs buffer deleted; LDS 24.5 KB.
// grid = 4096.  (Correctness of GT fusion verified in R6: absmax 4.88e-4.)
// ---------------------------------------------------------------------------
__global__ __launch_bounds__(256, 4) void kC(const float* __restrict__ x,
        const unsigned short* __restrict__ WqkvT,
        const unsigned short* __restrict__ GT,
        const float* __restrict__ bp, float* __restrict__ out)
{
    __shared__ __align__(16) unsigned short xs[32 * 392];   // x tile; reused as q̂ tile

    const int tid = threadIdx.x;
    const int w   = tid >> 6;
    const int l   = tid & 63;
    const int q   = l >> 4;
    const int c16 = l & 15;
    const int blk = blockIdx.x;
    const size_t tok0 = (size_t)blk * 32;
    const int b = blk >> 9;

    {   // stage x (non-temporal: block-exclusive rows)
        const int st = tid >> 3, sq = tid & 7;
        const float* xg = x + (tok0 + st) * 384 + sq * 4;
        unsigned short* xw = xs + st * 392 + sq * 4;
#pragma unroll
        for (int i = 0; i < 12; ++i) {
            f32x4 v = __builtin_nontemporal_load((const f32x4*)(xg + i * 32));
            us4 o; o.x = f2bf(v.x); o.y = f2bf(v.y); o.z = f2bf(v.z); o.w = f2bf(v.w);
            *(us4*)(xw + i * 32) = o;
        }
    }
    __syncthreads();

    // --- q-GEMM: 32 tok x 96 cols per wave (heads 2w, 2w+1), K=384 ---
    f32x4 acc[2][6];
#pragma unroll
    for (int mt = 0; mt < 2; ++mt)
#pragma unroll
        for (int j = 0; j < 6; ++j) acc[mt][j] = (f32x4){0.f, 0.f, 0.f, 0.f};

#pragma unroll
    for (int ks = 0; ks < 12; ++ks) {
        short8 a0 = *(const short8*)(xs + (c16) * 392 + ks * 32 + q * 8);
        short8 a1 = *(const short8*)(xs + (16 + c16) * 392 + ks * 32 + q * 8);
#pragma unroll
        for (int j = 0; j < 6; ++j) {
            const int nt = w * 6 + j;
            short8 bf = *(const short8*)(WqkvT + (size_t)(nt * 16 + c16) * 384 + ks * 32 + q * 8);
            acc[0][j] = MFMA(a0, bf, acc[0][j]);
            acc[1][j] = MFMA(a1, bf, acc[1][j]);
        }
    }
    __syncthreads();    // xs (x data) dead -> reuse for q̂

    // --- softmax over C=48 per (token, head); write q̂ into xs[t][h*48+c] ---
#pragma unroll
    for (int hh = 0; hh < 2; ++hh) {
        const int h = 2 * w + hh;
        f32x4 e[2][3];
#pragma unroll
        for (int mt = 0; mt < 2; ++mt)
#pragma unroll
            for (int jj = 0; jj < 3; ++jj) {
                f32x4 vv = acc[mt][hh * 3 + jj];
                e[mt][jj].x = __expf(vv.x); e[mt][jj].y = __expf(vv.y);
                e[mt][jj].z = __expf(vv.z); e[mt][jj].w = __expf(vv.w);
            }
#pragma unroll
        for (int mt = 0; mt < 2; ++mt)
#pragma unroll
            for (int r = 0; r < 4; ++r) {
                float ss = e[mt][0][r] + e[mt][1][r] + e[mt][2][r];
                ss += __shfl_xor(ss, 1); ss += __shfl_xor(ss, 2);
                ss += __shfl_xor(ss, 4); ss += __shfl_xor(ss, 8);
                const float inv = 1.0f / ss;
                e[mt][0][r] *= inv; e[mt][1][r] *= inv; e[mt][2][r] *= inv;
            }
#pragma unroll
        for (int mt = 0; mt < 2; ++mt)
#pragma unroll
            for (int jj = 0; jj < 3; ++jj) {
                const int c = jj * 16 + c16;
#pragma unroll
                for (int r = 0; r < 4; ++r) {
                    const int t = mt * 16 + q * 4 + r;
                    xs[t * 392 + h * 48 + c] = f2bf(e[mt][jj][r]);
                }
            }
    }
    __syncthreads();

    // --- proj: out = q̂ @ GT[b] + bias, K=384, 32 tok x 96 cols per wave ---
    f32x4 po[2][6];
#pragma unroll
    for (int mt = 0; mt < 2; ++mt)
#pragma unroll
        for (int j = 0; j < 6; ++j) po[mt][j] = (f32x4){0.f, 0.f, 0.f, 0.f};

#pragma unroll
    for (int ks = 0; ks < 12; ++ks) {
        short8 a0 = *(const short8*)(xs + (c16) * 392 + ks * 32 + q * 8);
        short8 a1 = *(const short8*)(xs + (16 + c16) * 392 + ks * 32 + q * 8);
#pragma unroll
        for (int j = 0; j < 6; ++j) {
            const int nt = w * 6 + j;
            short8 bf = *(const short8*)(GT + ((size_t)(b * 384 + nt * 16 + c16)) * 384 + ks * 32 + q * 8);
            po[0][j] = MFMA(a0, bf, po[0][j]);
            po[1][j] = MFMA(a1, bf, po[1][j]);
        }
    }

    // --- epilogue: bias + non-temporal store ---
#pragma unroll
    for (int j = 0; j < 6; ++j) {
        const int col = (w * 6 + j) * 16 + c16;
        const float bv = bp[col];
#pragma unroll
        for (int mt = 0; mt < 2; ++mt)
#pragma unroll
            for (int r = 0; r < 4; ++r) {
                const int t = mt * 16 + q * 4 + r;
                __builtin_nontemporal_store(po[mt][j][r] + bv,
                                            &out[(tok0 + t) * 384 + col]);
            }
    }
}

// ---------------------------------------------------------------------------
extern "C" void kernel_launch(void* const* d_in, const int* in_sizes, int n_in,
                              void* d_out, int out_size, void* d_ws, size_t ws_size,
                              hipStream_t stream)
{
    (void)in_sizes; (void)n_in; (void)out_size; (void)ws_size;
    const float* x    = (const float*)d_in[0];
    const float* Wqkv = (const float*)d_in[1];
    const float* Wp   = (const float*)d_in[2];
    const float* bp   = (const float*)d_in[3];
    float* out = (float*)d_out;

    char* p = (char*)d_ws;
    float* ctxP = (float*)p;                     p += (size_t)CTXP_ELEMS * 4;  // 18.87 MB
    float* ZP   = (float*)p;                     p += (size_t)ZP_ELEMS * 4;    // 393 KB
    unsigned short* WqkvT = (unsigned short*)p;  p += (size_t)TD_ * D_ * 2;    // 884736 B
    unsigned short* WpT   = (unsigned short*)p;  p += (size_t)D_ * D_ * 2;     // 294912 B
    unsigned short* GT    = (unsigned short*)p;                                // 2.36 MB

    kP<<<dim3(576), dim3(256), 0, stream>>>(Wqkv, Wp, WqkvT, WpT);
    kA<<<dim3(256), dim3(512), 0, stream>>>(x, WqkvT, ctxP, ZP);
    kG<<<dim3(64), dim3(384), 0, stream>>>(ctxP, ZP, WpT, GT);
    kC<<<dim3(4096), dim3(256), 0, stream>>>(x, WqkvT, GT, bp, out);
}